// Round 2
// baseline (2372.518 us; speedup 1.0000x reference)
//
#include <hip/hip_runtime.h>

#define C_CLASSES 1024
#define D_DIM     128
#define DCHUNK    32                     // columns per chunk
#define NCHUNK    (D_DIM / DCHUNK)       // 4
#define ROWBLOCKS 64                     // row-range blocks per chunk
#define BLOCK_SUM 1024                   // threads per sum block (16 waves)

typedef float v2f __attribute__((ext_vector_type(2)));

// ---------------------------------------------------------------------------
// Kernel 1: per-class counts via LDS histogram, flushed with global atomics.
// ---------------------------------------------------------------------------
__global__ __launch_bounds__(256) void count_kernel(const int* __restrict__ classes,
                                                    float* __restrict__ counts,
                                                    int N) {
    __shared__ unsigned int h[C_CLASSES];
    for (int i = threadIdx.x; i < C_CLASSES; i += blockDim.x) h[i] = 0u;
    __syncthreads();

    for (int r = blockIdx.x * blockDim.x + threadIdx.x; r < N;
         r += gridDim.x * blockDim.x) {
        atomicAdd(&h[classes[r]], 1u);
    }
    __syncthreads();

    for (int i = threadIdx.x; i < C_CLASSES; i += blockDim.x) {
        unsigned int v = h[i];
        if (v) atomicAdd(&counts[i], (float)v);
    }
}

// ---------------------------------------------------------------------------
// Kernel 2: segment sums. Each block owns a 32-wide column chunk and a row
// range; accumulates into a [1024][32] f32 LDS tile (128 KiB) via ds_add_f32,
// then flushes once with global atomics.
//   thread layout: col2 = tid & 15  -> float2 = cols [2*col2, 2*col2+1]
//                  rsub = tid >> 4  -> 64 rows in flight per iteration
//   global load:  8 B/lane, 512 B per wave (4 rows x 128 B contiguous)
//   LDS atomics:  bank = (col2*2+j) -> 16 banks/instr = 4-way (1.58x, m136);
//                 LDS pipe ~148K cyc/CU vs ~400K cyc/CU HBM budget -> not bound
// ---------------------------------------------------------------------------
__global__ __launch_bounds__(BLOCK_SUM) void sum_kernel(const float* __restrict__ x,
                                                        const int* __restrict__ classes,
                                                        float* __restrict__ out,
                                                        int N) {
    __shared__ float acc[C_CLASSES * DCHUNK];   // 128 KiB -> 1 block/CU, 16 waves

    const int rb    = blockIdx.x % ROWBLOCKS;
    const int chunk = blockIdx.x / ROWBLOCKS;   // 0..3

    for (int i = threadIdx.x; i < C_CLASSES * DCHUNK; i += BLOCK_SUM) acc[i] = 0.0f;
    __syncthreads();

    const int rows_per_block = (N + ROWBLOCKS - 1) / ROWBLOCKS;   // 31250
    const int r0 = rb * rows_per_block;
    const int r1 = (r0 + rows_per_block < N) ? (r0 + rows_per_block) : N;

    const int col2  = threadIdx.x & 15;               // 0..15 (float2 column pair)
    const int rsub  = threadIdx.x >> 4;               // 0..63
    const int rstep = BLOCK_SUM / 16;                 // 64 rows / iteration

    const float* __restrict__ xc = x + (size_t)chunk * DCHUNK;

    #pragma unroll 4
    for (int r = r0 + rsub; r < r1; r += rstep) {
        int c = classes[r];                            // broadcast across 16 lanes
        // nontemporal: x is a pure 1 GB stream, keep L2/L3 for classes
        v2f v = __builtin_nontemporal_load(
                    (const v2f*)(xc + (size_t)r * D_DIM) + col2);
        float* a = &acc[c * DCHUNK + col2 * 2];
        atomicAdd(a,     v.x);                         // ds_add_f32
        atomicAdd(a + 1, v.y);
    }
    __syncthreads();

    // flush: acc[class][col] -> out[class][chunk*32 + col]
    for (int i = threadIdx.x; i < C_CLASSES * DCHUNK; i += BLOCK_SUM) {
        int cls = i >> 5;
        int cc  = i & 31;
        atomicAdd(&out[cls * D_DIM + chunk * DCHUNK + cc], acc[i]);
    }
}

// ---------------------------------------------------------------------------
// Kernel 3: divide sums by counts.
// ---------------------------------------------------------------------------
__global__ __launch_bounds__(256) void div_kernel(float* __restrict__ out,
                                                  const float* __restrict__ counts) {
    int i = blockIdx.x * blockDim.x + threadIdx.x;    // < C*D
    out[i] = out[i] / counts[i >> 7];                 // i>>7 == i / 128
}

extern "C" void kernel_launch(void* const* d_in, const int* in_sizes, int n_in,
                              void* d_out, int out_size, void* d_ws, size_t ws_size,
                              hipStream_t stream) {
    const float* x       = (const float*)d_in[0];
    const int*   classes = (const int*)d_in[1];
    float*       out     = (float*)d_out;     // [1024][128]
    float*       counts  = (float*)d_ws;      // [1024]

    const int N = in_sizes[1];                // 2,000,000 rows

    // d_out / d_ws are poisoned with 0xAA before every timed launch — re-zero.
    hipMemsetAsync(out, 0, (size_t)C_CLASSES * D_DIM * sizeof(float), stream);
    hipMemsetAsync(counts, 0, (size_t)C_CLASSES * sizeof(float), stream);

    count_kernel<<<256, 256, 0, stream>>>(classes, counts, N);
    sum_kernel<<<NCHUNK * ROWBLOCKS, BLOCK_SUM, 0, stream>>>(x, classes, out, N);
    div_kernel<<<(C_CLASSES * D_DIM) / 256, 256, 0, stream>>>(out, counts);
}